// Round 2
// baseline (44672.437 us; speedup 1.0000x reference)
//
#include <hip/hip_runtime.h>
#include <utility>

#define HID 256

// Topology constants for GRID_N=80 (verified: E2=2*E1+3*F1, E3=2*E2+3*F2)
constexpr size_t MAXN3 = 100489;

// Static device scratch (BSS, allocated at module load — graph-capture safe).
__device__ float g_A [MAXN3 * 256];
__device__ float g_B [MAXN3 * 256];
__device__ float g_Hb[MAXN3 * 256];
__device__ float g_VA[MAXN3 * 128];
__device__ float g_C0[MAXN3 * 3];
__device__ float g_C2[MAXN3 * 3];
__device__ float g_Vv[MAXN3 * 3];
__device__ float g_T [56 * 56 * 128];

// ---------------- kernels ----------------

__global__ __launch_bounds__(128) void k_transpose(const float* __restrict__ in,
                                                   float* __restrict__ out, int HW) {
  int p = blockIdx.x;
  int c = threadIdx.x;
  if (p < HW) out[(size_t)p * 128 + c] = in[(size_t)c * HW + p];
}

__global__ __launch_bounds__(128) void k_vert_align(const float* __restrict__ fT,
                                                    const float* __restrict__ verts,
                                                    float* __restrict__ out,
                                                    int N, int H, int W) {
  int v = blockIdx.x;
  if (v >= N) return;
  int c = threadIdx.x;
  float vx = verts[(size_t)v * 3 + 0];
  float vy = verts[(size_t)v * 3 + 1];
  float fx = (vx + 1.f) * 0.5f * (float)(W - 1);
  float fy = (vy + 1.f) * 0.5f * (float)(H - 1);
  float x0f = floorf(fx), y0f = floorf(fy);
  float wx = fx - x0f, wy = fy - y0f;
  int x0 = (int)x0f, y0 = (int)y0f;
  float acc = 0.f;
#pragma unroll
  for (int dy = 0; dy < 2; ++dy) {
#pragma unroll
    for (int dx = 0; dx < 2; ++dx) {
      int yi = y0 + dy, xi = x0 + dx;
      bool valid = (yi >= 0) && (yi < H) && (xi >= 0) && (xi < W);
      int yc = min(max(yi, 0), H - 1);
      int xc = min(max(xi, 0), W - 1);
      float val = fT[((size_t)yc * W + xc) * 128 + c];
      float wgt = (dy ? wy : 1.f - wy) * (dx ? wx : 1.f - wx);
      acc += valid ? val * wgt : 0.f;
    }
  }
  out[(size_t)v * 128 + c] = acc;
}

// Y[N x 256] = X[N x K] @ W[K x 256] (+ bias | += )
template <int K, bool ACC>
__global__ __launch_bounds__(256) void k_matmul(const float* __restrict__ X,
                                                const float* __restrict__ W,
                                                const float* __restrict__ bias,
                                                float* __restrict__ Y, int N) {
  __shared__ float Xs[64][17];
  __shared__ float Ws[16][64];
  int tid = threadIdx.x;
  int tx = tid & 15, ty = tid >> 4;
  int row0 = blockIdx.y * 64;
  int col0 = blockIdx.x * 64;
  float acc[4][4] = {};
  for (int k0 = 0; k0 < K; k0 += 16) {
#pragma unroll
    for (int it = 0; it < 4; ++it) {
      int t = tid + it * 256;
      int r = t >> 4, kk = t & 15;
      int row = row0 + r;
      Xs[r][kk] = (row < N) ? X[(size_t)row * K + k0 + kk] : 0.f;
    }
#pragma unroll
    for (int it = 0; it < 4; ++it) {
      int t = tid + it * 256;
      int kk = t >> 6, cc = t & 63;
      Ws[kk][cc] = W[(size_t)(k0 + kk) * HID + col0 + cc];
    }
    __syncthreads();
#pragma unroll
    for (int kk = 0; kk < 16; ++kk) {
      float a[4], bv[4];
#pragma unroll
      for (int i = 0; i < 4; ++i) a[i] = Xs[ty * 4 + i][kk];
#pragma unroll
      for (int j = 0; j < 4; ++j) bv[j] = Ws[kk][tx * 4 + j];
#pragma unroll
      for (int i = 0; i < 4; ++i)
#pragma unroll
        for (int j = 0; j < 4; ++j) acc[i][j] += a[i] * bv[j];
    }
    __syncthreads();
  }
#pragma unroll
  for (int i = 0; i < 4; ++i) {
    int row = row0 + ty * 4 + i;
    if (row >= N) continue;
#pragma unroll
    for (int j = 0; j < 4; ++j) {
      int col = col0 + tx * 4 + j;
      if (ACC) {
        Y[(size_t)row * HID + col] += acc[i][j];
      } else {
        Y[(size_t)row * HID + col] = acc[i][j] + bias[col];
      }
    }
  }
}

// OUT[a] += H[b]; OUT[b] += H[a]  per edge, 256 channels (64 thr/edge x float4)
__global__ __launch_bounds__(256) void k_scatter256(const int* __restrict__ edges,
                                                    const float* __restrict__ H,
                                                    float* __restrict__ OUT, int E) {
  int idx = blockIdx.x * blockDim.x + threadIdx.x;
  int e = idx >> 6;
  if (e >= E) return;
  int c = (idx & 63) * 4;
  int a = edges[(size_t)e * 2 + 0];
  int b = edges[(size_t)e * 2 + 1];
  float4 hb = *(const float4*)(H + (size_t)b * HID + c);
  float4 ha = *(const float4*)(H + (size_t)a * HID + c);
  float* oa = OUT + (size_t)a * HID + c;
  float* ob = OUT + (size_t)b * HID + c;
  atomicAdd(oa + 0, hb.x);
  atomicAdd(oa + 1, hb.y);
  atomicAdd(oa + 2, hb.z);
  atomicAdd(oa + 3, hb.w);
  atomicAdd(ob + 0, ha.x);
  atomicAdd(ob + 1, ha.y);
  atomicAdd(ob + 2, ha.z);
  atomicAdd(ob + 3, ha.w);
}

// Y[N x 3] = X[N x 256] @ W[256 x 3] + b  (one wave per row)
__global__ __launch_bounds__(256) void k_rowdot3(const float* __restrict__ X,
                                                 const float* __restrict__ W,
                                                 const float* __restrict__ b,
                                                 float* __restrict__ Y, int N) {
  int gid = blockIdx.x * blockDim.x + threadIdx.x;
  int row = gid >> 6;
  int lane = threadIdx.x & 63;
  if (row >= N) return;
  float4 xv = ((const float4*)(X + (size_t)row * HID))[lane];
  float s0 = 0.f, s1 = 0.f, s2 = 0.f;
#pragma unroll
  for (int k = 0; k < 4; ++k) {
    float x = (&xv.x)[k];
    int kk = lane * 4 + k;
    s0 += x * W[kk * 3 + 0];
    s1 += x * W[kk * 3 + 1];
    s2 += x * W[kk * 3 + 2];
  }
#pragma unroll
  for (int off = 32; off > 0; off >>= 1) {
    s0 += __shfl_down(s0, off);
    s1 += __shfl_down(s1, off);
    s2 += __shfl_down(s2, off);
  }
  if (lane == 0) {
    Y[(size_t)row * 3 + 0] = s0 + b[0];
    Y[(size_t)row * 3 + 1] = s1 + b[1];
    Y[(size_t)row * 3 + 2] = s2 + b[2];
  }
}

__global__ __launch_bounds__(256) void k_scatter3(const int* __restrict__ edges,
                                                  const float* __restrict__ H,
                                                  float* __restrict__ OUT, int E) {
  int e = blockIdx.x * blockDim.x + threadIdx.x;
  if (e >= E) return;
  int a = edges[(size_t)e * 2 + 0];
  int b = edges[(size_t)e * 2 + 1];
#pragma unroll
  for (int k = 0; k < 3; ++k) {
    atomicAdd(&OUT[(size_t)a * 3 + k], H[(size_t)b * 3 + k]);
    atomicAdd(&OUT[(size_t)b * 3 + k], H[(size_t)a * 3 + k]);
  }
}

__global__ __launch_bounds__(256) void k_subdiv3(const float* __restrict__ c,
                                                 const int* __restrict__ edges,
                                                 float* __restrict__ v, int N, int E) {
  int i = blockIdx.x * blockDim.x + threadIdx.x;
  if (i >= N + E) return;
  if (i < N) {
#pragma unroll
    for (int k = 0; k < 3; ++k) v[(size_t)i * 3 + k] = c[(size_t)i * 3 + k];
  } else {
    int e = i - N;
    int a = edges[(size_t)e * 2 + 0];
    int b = edges[(size_t)e * 2 + 1];
#pragma unroll
    for (int k = 0; k < 3; ++k)
      v[(size_t)i * 3 + k] = 0.5f * (c[(size_t)a * 3 + k] + c[(size_t)b * 3 + k]);
  }
}

__global__ __launch_bounds__(256) void k_subdiv_feat(const float* __restrict__ x,
                                                     const int* __restrict__ edges,
                                                     float* __restrict__ out, int N, int E) {
  int idx = blockIdx.x * blockDim.x + threadIdx.x;
  int v = idx >> 6;
  if (v >= N + E) return;
  int c = (idx & 63) * 4;
  float4 r;
  if (v < N) {
    r = *(const float4*)(x + (size_t)v * HID + c);
  } else {
    int e = v - N;
    int a = edges[(size_t)e * 2 + 0];
    int b = edges[(size_t)e * 2 + 1];
    float4 xa = *(const float4*)(x + (size_t)a * HID + c);
    float4 xb = *(const float4*)(x + (size_t)b * HID + c);
    r = make_float4(0.5f * (xa.x + xb.x), 0.5f * (xa.y + xb.y),
                    0.5f * (xa.z + xb.z), 0.5f * (xa.w + xb.w));
  }
  *(float4*)(out + (size_t)v * HID + c) = r;
}

// ---------------- launcher ----------------

extern "C" void kernel_launch(void* const* d_in, const int* in_sizes, int n_in,
                              void* d_out, int out_size, void* d_ws, size_t ws_size,
                              hipStream_t stream) {
  const float* conv64  = (const float*)d_in[0];
  const float* conv128 = (const float*)d_in[1];
  const float* conv256 = (const float*)d_in[2];
  const float* verts0  = (const float*)d_in[3];
  const int*   edges1  = (const int*)d_in[4];
  const int*   edges2  = (const int*)d_in[5];
  const int*   edges3  = (const int*)d_in[6];
  const float* w_in1 = (const float*)d_in[7],  *b_in1 = (const float*)d_in[8];
  const float* w_h1  = (const float*)d_in[9],  *b_h1  = (const float*)d_in[10];
  const float* w_out1= (const float*)d_in[11], *b_out1= (const float*)d_in[12];
  const float* w_in2 = (const float*)d_in[13], *b_in2 = (const float*)d_in[14];
  const float* w_h2  = (const float*)d_in[15], *b_h2  = (const float*)d_in[16];
  const float* w_out2= (const float*)d_in[17], *b_out2= (const float*)d_in[18];
  const float* w_in3 = (const float*)d_in[19], *b_in3 = (const float*)d_in[20];
  const float* w_h3  = (const float*)d_in[21], *b_h3  = (const float*)d_in[22];
  const float* w_out3= (const float*)d_in[23], *b_out3= (const float*)d_in[24];

  const int N1 = in_sizes[3] / 3;
  const int E1 = in_sizes[4] / 2;
  const int E2 = in_sizes[5] / 2;
  const int E3 = in_sizes[6] / 2;
  const int N2 = N1 + E1;
  const int N3 = N2 + E2;
  if ((size_t)N3 > MAXN3) return;  // topology sanity (cannot happen for GRID_N=80)

  float *A, *B, *Hb, *VA, *C0, *C2, *Vv, *T;
  hipGetSymbolAddress((void**)&A,  HIP_SYMBOL(g_A));
  hipGetSymbolAddress((void**)&B,  HIP_SYMBOL(g_B));
  hipGetSymbolAddress((void**)&Hb, HIP_SYMBOL(g_Hb));
  hipGetSymbolAddress((void**)&VA, HIP_SYMBOL(g_VA));
  hipGetSymbolAddress((void**)&C0, HIP_SYMBOL(g_C0));
  hipGetSymbolAddress((void**)&C2, HIP_SYMBOL(g_C2));
  hipGetSymbolAddress((void**)&Vv, HIP_SYMBOL(g_Vv));
  hipGetSymbolAddress((void**)&T,  HIP_SYMBOL(g_T));

  auto mmGrid = [](int N) { return dim3(4, (unsigned)((N + 63) / 64)); };

  auto gconv_hidden = [&](float*& X, float*& Y, const float* wh, const float* bh,
                          const int* edges, int E, int N) {
    for (int l = 0; l < 12; ++l) {
      const float* w0 = wh + (size_t)l * 2 * HID * HID;
      const float* w1 = w0 + (size_t)HID * HID;
      const float* b0 = bh + (size_t)l * 2 * HID;
      const float* b1 = b0 + HID;
      k_matmul<HID, false><<<mmGrid(N), 256, 0, stream>>>(X, w0, b0, Y, N);
      k_matmul<HID, false><<<mmGrid(N), 256, 0, stream>>>(X, w1, b1, Hb, N);
      k_scatter256<<<((size_t)E * 64 + 255) / 256, 256, 0, stream>>>(edges, Hb, Y, E);
      std::swap(X, Y);
    }
  };

  auto gconv_out = [&](const float* X, const float* wo, const float* bo,
                       float* Cdst, const int* edges, int E, int N) {
    k_rowdot3<<<((size_t)N * 64 + 255) / 256, 256, 0, stream>>>(X, wo, bo, Cdst, N);
    k_rowdot3<<<((size_t)N * 64 + 255) / 256, 256, 0, stream>>>(X, wo + HID * 3, bo + 3, C2, N);
    k_scatter3<<<(E + 255) / 256, 256, 0, stream>>>(edges, C2, Cdst, E);
  };

  float* Xc; float* Yc;

  // ---------- Stage 1 ----------
  k_transpose<<<56 * 56, 128, 0, stream>>>(conv64, T, 56 * 56);
  k_vert_align<<<N1, 128, 0, stream>>>(T, verts0, VA, N1, 56, 56);
  k_matmul<128, false><<<mmGrid(N1), 256, 0, stream>>>(VA, w_in1, b_in1, A, N1);
  k_matmul<128, false><<<mmGrid(N1), 256, 0, stream>>>(VA, w_in1 + 128 * HID, b_in1 + HID, Hb, N1);
  k_scatter256<<<((size_t)E1 * 64 + 255) / 256, 256, 0, stream>>>(edges1, Hb, A, E1);
  Xc = A; Yc = B;
  gconv_hidden(Xc, Yc, w_h1, b_h1, edges1, E1, N1);   // x ends in Xc
  gconv_out(Xc, w_out1, b_out1, C0, edges1, E1, N1);  // c1 in C0
  k_subdiv3<<<(N2 + 255) / 256, 256, 0, stream>>>(C0, edges1, Vv, N1, E1);       // v2
  k_subdiv_feat<<<((size_t)N2 * 64 + 255) / 256, 256, 0, stream>>>(Xc, edges1, Yc, N1, E1); // hs in Yc

  // ---------- Stage 2 ----------
  k_transpose<<<28 * 28, 128, 0, stream>>>(conv128, T, 28 * 28);
  k_vert_align<<<N2, 128, 0, stream>>>(T, Vv, VA, N2, 28, 28);
  {
    float* hs = Yc; float* X0 = Xc;  // write h0 into X0 (old x dead)
    k_matmul<128, false><<<mmGrid(N2), 256, 0, stream>>>(VA, w_in2, b_in2, X0, N2);
    k_matmul<HID, true ><<<mmGrid(N2), 256, 0, stream>>>(hs, w_in2 + 128 * HID, nullptr, X0, N2);
    k_matmul<128, false><<<mmGrid(N2), 256, 0, stream>>>(VA, w_in2 + 384 * HID, b_in2 + HID, Hb, N2);
    k_matmul<HID, true ><<<mmGrid(N2), 256, 0, stream>>>(hs, w_in2 + 384 * HID + 128 * HID, nullptr, Hb, N2);
    k_scatter256<<<((size_t)E2 * 64 + 255) / 256, 256, 0, stream>>>(edges2, Hb, X0, E2);
  }
  gconv_hidden(Xc, Yc, w_h2, b_h2, edges2, E2, N2);
  gconv_out(Xc, w_out2, b_out2, C0, edges2, E2, N2);  // c2 in C0
  k_subdiv3<<<(N3 + 255) / 256, 256, 0, stream>>>(C0, edges2, Vv, N2, E2);       // v3
  k_subdiv_feat<<<((size_t)N3 * 64 + 255) / 256, 256, 0, stream>>>(Xc, edges2, Yc, N2, E2); // hs

  // ---------- Stage 3 ----------
  k_transpose<<<14 * 14, 128, 0, stream>>>(conv256, T, 14 * 14);
  k_vert_align<<<N3, 128, 0, stream>>>(T, Vv, VA, N3, 14, 14);
  {
    float* hs = Yc; float* X0 = Xc;
    k_matmul<128, false><<<mmGrid(N3), 256, 0, stream>>>(VA, w_in3, b_in3, X0, N3);
    k_matmul<HID, true ><<<mmGrid(N3), 256, 0, stream>>>(hs, w_in3 + 128 * HID, nullptr, X0, N3);
    k_matmul<128, false><<<mmGrid(N3), 256, 0, stream>>>(VA, w_in3 + 384 * HID, b_in3 + HID, Hb, N3);
    k_matmul<HID, true ><<<mmGrid(N3), 256, 0, stream>>>(hs, w_in3 + 384 * HID + 128 * HID, nullptr, Hb, N3);
    k_scatter256<<<((size_t)E3 * 64 + 255) / 256, 256, 0, stream>>>(edges3, Hb, X0, E3);
  }
  gconv_hidden(Xc, Yc, w_h3, b_h3, edges3, E3, N3);
  // final coords straight into d_out
  float* OUT = (float*)d_out;
  k_rowdot3<<<((size_t)N3 * 64 + 255) / 256, 256, 0, stream>>>(Xc, w_out3, b_out3, OUT, N3);
  k_rowdot3<<<((size_t)N3 * 64 + 255) / 256, 256, 0, stream>>>(Xc, w_out3 + HID * 3, b_out3 + 3, C2, N3);
  k_scatter3<<<(E3 + 255) / 256, 256, 0, stream>>>(edges3, C2, OUT, E3);
}

// Round 3
// 9704.375 us; speedup vs baseline: 4.6033x; 4.6033x over previous
//
#include <hip/hip_runtime.h>
#include <utility>

#define HID 256

// Topology constants for GRID_N=80
constexpr size_t MAXN3 = 100489;
constexpr size_t MAXE3 = 300200;

// Static device scratch (BSS, allocated at module load — graph-capture safe).
__device__ float g_A [MAXN3 * 256];
__device__ float g_B [MAXN3 * 256];
__device__ float g_Hb[MAXN3 * 256];
__device__ float g_VA[MAXN3 * 128];
__device__ float g_C0[MAXN3 * 3];
__device__ float g_C2[MAXN3 * 3];
__device__ float g_Vv[MAXN3 * 3];
__device__ float g_T [56 * 56 * 128];
// CSR scratch
__device__ int g_deg   [MAXN3];
__device__ int g_rowptr[MAXN3 + 1];
__device__ int g_cursor[MAXN3];
__device__ int g_adj   [2 * MAXE3];

// ---------------- CSR build ----------------

__global__ __launch_bounds__(256) void k_count(const int* __restrict__ edges,
                                               int* __restrict__ deg, int E) {
  int e = blockIdx.x * blockDim.x + threadIdx.x;
  if (e >= E) return;
  atomicAdd(&deg[edges[2 * e + 0]], 1);
  atomicAdd(&deg[edges[2 * e + 1]], 1);
}

// single-block chunked exclusive scan: deg[0..N) -> rowptr[0..N], cursor copy
__global__ __launch_bounds__(1024) void k_scan(const int* __restrict__ deg,
                                               int* __restrict__ rowptr,
                                               int* __restrict__ cursor, int N) {
  __shared__ int sums[1024];
  int t = threadIdx.x;
  int chunk = (N + 1023) / 1024;
  int lo = t * chunk;
  int hi = min(lo + chunk, N);
  int s = 0;
  for (int i = lo; i < hi; ++i) s += deg[i];
  sums[t] = s;
  __syncthreads();
  for (int off = 1; off < 1024; off <<= 1) {
    int v = (t >= off) ? sums[t - off] : 0;
    __syncthreads();
    sums[t] += v;
    __syncthreads();
  }
  int base = (t == 0) ? 0 : sums[t - 1];
  for (int i = lo; i < hi; ++i) {
    rowptr[i] = base;
    cursor[i] = base;
    base += deg[i];
  }
  if (t == 1023) rowptr[N] = sums[1023];
}

__global__ __launch_bounds__(256) void k_fill(const int* __restrict__ edges,
                                              int* __restrict__ cursor,
                                              int* __restrict__ adj, int E) {
  int e = blockIdx.x * blockDim.x + threadIdx.x;
  if (e >= E) return;
  int a = edges[2 * e + 0];
  int b = edges[2 * e + 1];
  adj[atomicAdd(&cursor[a], 1)] = b;
  adj[atomicAdd(&cursor[b], 1)] = a;
}

// ---------------- kernels ----------------

__global__ __launch_bounds__(128) void k_transpose(const float* __restrict__ in,
                                                   float* __restrict__ out, int HW) {
  int p = blockIdx.x;
  int c = threadIdx.x;
  if (p < HW) out[(size_t)p * 128 + c] = in[(size_t)c * HW + p];
}

__global__ __launch_bounds__(128) void k_vert_align(const float* __restrict__ fT,
                                                    const float* __restrict__ verts,
                                                    float* __restrict__ out,
                                                    int N, int H, int W) {
  int v = blockIdx.x;
  if (v >= N) return;
  int c = threadIdx.x;
  float vx = verts[(size_t)v * 3 + 0];
  float vy = verts[(size_t)v * 3 + 1];
  float fx = (vx + 1.f) * 0.5f * (float)(W - 1);
  float fy = (vy + 1.f) * 0.5f * (float)(H - 1);
  float x0f = floorf(fx), y0f = floorf(fy);
  float wx = fx - x0f, wy = fy - y0f;
  int x0 = (int)x0f, y0 = (int)y0f;
  float acc = 0.f;
#pragma unroll
  for (int dy = 0; dy < 2; ++dy) {
#pragma unroll
    for (int dx = 0; dx < 2; ++dx) {
      int yi = y0 + dy, xi = x0 + dx;
      bool valid = (yi >= 0) && (yi < H) && (xi >= 0) && (xi < W);
      int yc = min(max(yi, 0), H - 1);
      int xc = min(max(xi, 0), W - 1);
      float val = fT[((size_t)yc * W + xc) * 128 + c];
      float wgt = (dy ? wy : 1.f - wy) * (dx ? wx : 1.f - wx);
      acc += valid ? val * wgt : 0.f;
    }
  }
  out[(size_t)v * 128 + c] = acc;
}

// Fused pair: Y0 = X@W0 (+b0 | +=), Y1 = X@W1 (+b1 | +=)
template <int K, bool ACC>
__global__ __launch_bounds__(256) void k_matmul2(const float* __restrict__ X,
                                                 const float* __restrict__ W0,
                                                 const float* __restrict__ W1,
                                                 const float* __restrict__ b0,
                                                 const float* __restrict__ b1,
                                                 float* __restrict__ Y0,
                                                 float* __restrict__ Y1, int N) {
  __shared__ float Xs[64][17];
  __shared__ float Ws0[16][64];
  __shared__ float Ws1[16][64];
  int tid = threadIdx.x;
  int tx = tid & 15, ty = tid >> 4;
  int row0 = blockIdx.y * 64;
  int col0 = blockIdx.x * 64;
  float acc0[4][4] = {};
  float acc1[4][4] = {};
  for (int k0 = 0; k0 < K; k0 += 16) {
#pragma unroll
    for (int it = 0; it < 4; ++it) {
      int t = tid + it * 256;
      int r = t >> 4, kk = t & 15;
      int row = row0 + r;
      Xs[r][kk] = (row < N) ? X[(size_t)row * K + k0 + kk] : 0.f;
    }
#pragma unroll
    for (int it = 0; it < 4; ++it) {
      int t = tid + it * 256;
      int kk = t >> 6, cc = t & 63;
      Ws0[kk][cc] = W0[(size_t)(k0 + kk) * HID + col0 + cc];
      Ws1[kk][cc] = W1[(size_t)(k0 + kk) * HID + col0 + cc];
    }
    __syncthreads();
#pragma unroll
    for (int kk = 0; kk < 16; ++kk) {
      float a[4], bv0[4], bv1[4];
#pragma unroll
      for (int i = 0; i < 4; ++i) a[i] = Xs[ty * 4 + i][kk];
#pragma unroll
      for (int j = 0; j < 4; ++j) { bv0[j] = Ws0[kk][tx * 4 + j]; bv1[j] = Ws1[kk][tx * 4 + j]; }
#pragma unroll
      for (int i = 0; i < 4; ++i)
#pragma unroll
        for (int j = 0; j < 4; ++j) {
          acc0[i][j] += a[i] * bv0[j];
          acc1[i][j] += a[i] * bv1[j];
        }
    }
    __syncthreads();
  }
#pragma unroll
  for (int i = 0; i < 4; ++i) {
    int row = row0 + ty * 4 + i;
    if (row >= N) continue;
#pragma unroll
    for (int j = 0; j < 4; ++j) {
      int col = col0 + tx * 4 + j;
      if (ACC) {
        Y0[(size_t)row * HID + col] += acc0[i][j];
        Y1[(size_t)row * HID + col] += acc1[i][j];
      } else {
        Y0[(size_t)row * HID + col] = acc0[i][j] + b0[col];
        Y1[(size_t)row * HID + col] = acc1[i][j] + b1[col];
      }
    }
  }
}

// Y[v] += sum_{u in adj(v)} H[u]   (64 threads per vertex, float4 per thread)
__global__ __launch_bounds__(256) void k_gather256(const int* __restrict__ rowptr,
                                                   const int* __restrict__ adj,
                                                   const float* __restrict__ H,
                                                   float* __restrict__ Y, int N) {
  int idx = blockIdx.x * blockDim.x + threadIdx.x;
  int v = idx >> 6;
  if (v >= N) return;
  int c = (threadIdx.x & 63) * 4;
  int lo = rowptr[v], hi = rowptr[v + 1];
  float* yp = Y + (size_t)v * HID + c;
  float4 acc = *(float4*)yp;
  for (int i = lo; i < hi; ++i) {
    float4 h = *(const float4*)(H + (size_t)adj[i] * HID + c);
    acc.x += h.x; acc.y += h.y; acc.z += h.z; acc.w += h.w;
  }
  *(float4*)yp = acc;
}

// Y[N x 3] = X[N x 256] @ W[256 x 3] + b  (one wave per row)
__global__ __launch_bounds__(256) void k_rowdot3(const float* __restrict__ X,
                                                 const float* __restrict__ W,
                                                 const float* __restrict__ b,
                                                 float* __restrict__ Y, int N) {
  int gid = blockIdx.x * blockDim.x + threadIdx.x;
  int row = gid >> 6;
  int lane = threadIdx.x & 63;
  if (row >= N) return;
  float4 xv = ((const float4*)(X + (size_t)row * HID))[lane];
  float s0 = 0.f, s1 = 0.f, s2 = 0.f;
#pragma unroll
  for (int k = 0; k < 4; ++k) {
    float x = (&xv.x)[k];
    int kk = lane * 4 + k;
    s0 += x * W[kk * 3 + 0];
    s1 += x * W[kk * 3 + 1];
    s2 += x * W[kk * 3 + 2];
  }
#pragma unroll
  for (int off = 32; off > 0; off >>= 1) {
    s0 += __shfl_down(s0, off);
    s1 += __shfl_down(s1, off);
    s2 += __shfl_down(s2, off);
  }
  if (lane == 0) {
    Y[(size_t)row * 3 + 0] = s0 + b[0];
    Y[(size_t)row * 3 + 1] = s1 + b[1];
    Y[(size_t)row * 3 + 2] = s2 + b[2];
  }
}

__global__ __launch_bounds__(256) void k_scatter3(const int* __restrict__ edges,
                                                  const float* __restrict__ H,
                                                  float* __restrict__ OUT, int E) {
  int e = blockIdx.x * blockDim.x + threadIdx.x;
  if (e >= E) return;
  int a = edges[(size_t)e * 2 + 0];
  int b = edges[(size_t)e * 2 + 1];
#pragma unroll
  for (int k = 0; k < 3; ++k) {
    atomicAdd(&OUT[(size_t)a * 3 + k], H[(size_t)b * 3 + k]);
    atomicAdd(&OUT[(size_t)b * 3 + k], H[(size_t)a * 3 + k]);
  }
}

__global__ __launch_bounds__(256) void k_subdiv3(const float* __restrict__ c,
                                                 const int* __restrict__ edges,
                                                 float* __restrict__ v, int N, int E) {
  int i = blockIdx.x * blockDim.x + threadIdx.x;
  if (i >= N + E) return;
  if (i < N) {
#pragma unroll
    for (int k = 0; k < 3; ++k) v[(size_t)i * 3 + k] = c[(size_t)i * 3 + k];
  } else {
    int e = i - N;
    int a = edges[(size_t)e * 2 + 0];
    int b = edges[(size_t)e * 2 + 1];
#pragma unroll
    for (int k = 0; k < 3; ++k)
      v[(size_t)i * 3 + k] = 0.5f * (c[(size_t)a * 3 + k] + c[(size_t)b * 3 + k]);
  }
}

__global__ __launch_bounds__(256) void k_subdiv_feat(const float* __restrict__ x,
                                                     const int* __restrict__ edges,
                                                     float* __restrict__ out, int N, int E) {
  int idx = blockIdx.x * blockDim.x + threadIdx.x;
  int v = idx >> 6;
  if (v >= N + E) return;
  int c = (threadIdx.x & 63) * 4;
  float4 r;
  if (v < N) {
    r = *(const float4*)(x + (size_t)v * HID + c);
  } else {
    int e = v - N;
    int a = edges[(size_t)e * 2 + 0];
    int b = edges[(size_t)e * 2 + 1];
    float4 xa = *(const float4*)(x + (size_t)a * HID + c);
    float4 xb = *(const float4*)(x + (size_t)b * HID + c);
    r = make_float4(0.5f * (xa.x + xb.x), 0.5f * (xa.y + xb.y),
                    0.5f * (xa.z + xb.z), 0.5f * (xa.w + xb.w));
  }
  *(float4*)(out + (size_t)v * HID + c) = r;
}

// ---------------- launcher ----------------

extern "C" void kernel_launch(void* const* d_in, const int* in_sizes, int n_in,
                              void* d_out, int out_size, void* d_ws, size_t ws_size,
                              hipStream_t stream) {
  const float* conv64  = (const float*)d_in[0];
  const float* conv128 = (const float*)d_in[1];
  const float* conv256 = (const float*)d_in[2];
  const float* verts0  = (const float*)d_in[3];
  const int*   edges1  = (const int*)d_in[4];
  const int*   edges2  = (const int*)d_in[5];
  const int*   edges3  = (const int*)d_in[6];
  const float* w_in1 = (const float*)d_in[7],  *b_in1 = (const float*)d_in[8];
  const float* w_h1  = (const float*)d_in[9],  *b_h1  = (const float*)d_in[10];
  const float* w_out1= (const float*)d_in[11], *b_out1= (const float*)d_in[12];
  const float* w_in2 = (const float*)d_in[13], *b_in2 = (const float*)d_in[14];
  const float* w_h2  = (const float*)d_in[15], *b_h2  = (const float*)d_in[16];
  const float* w_out2= (const float*)d_in[17], *b_out2= (const float*)d_in[18];
  const float* w_in3 = (const float*)d_in[19], *b_in3 = (const float*)d_in[20];
  const float* w_h3  = (const float*)d_in[21], *b_h3  = (const float*)d_in[22];
  const float* w_out3= (const float*)d_in[23], *b_out3= (const float*)d_in[24];

  const int N1 = in_sizes[3] / 3;
  const int E1 = in_sizes[4] / 2;
  const int E2 = in_sizes[5] / 2;
  const int E3 = in_sizes[6] / 2;
  const int N2 = N1 + E1;
  const int N3 = N2 + E2;
  if ((size_t)N3 > MAXN3 || (size_t)E3 > MAXE3) return;

  float *A, *B, *Hb, *VA, *C0, *C2, *Vv, *T;
  int *deg, *rowptr, *cursor, *adj;
  hipGetSymbolAddress((void**)&A,  HIP_SYMBOL(g_A));
  hipGetSymbolAddress((void**)&B,  HIP_SYMBOL(g_B));
  hipGetSymbolAddress((void**)&Hb, HIP_SYMBOL(g_Hb));
  hipGetSymbolAddress((void**)&VA, HIP_SYMBOL(g_VA));
  hipGetSymbolAddress((void**)&C0, HIP_SYMBOL(g_C0));
  hipGetSymbolAddress((void**)&C2, HIP_SYMBOL(g_C2));
  hipGetSymbolAddress((void**)&Vv, HIP_SYMBOL(g_Vv));
  hipGetSymbolAddress((void**)&T,  HIP_SYMBOL(g_T));
  hipGetSymbolAddress((void**)&deg,    HIP_SYMBOL(g_deg));
  hipGetSymbolAddress((void**)&rowptr, HIP_SYMBOL(g_rowptr));
  hipGetSymbolAddress((void**)&cursor, HIP_SYMBOL(g_cursor));
  hipGetSymbolAddress((void**)&adj,    HIP_SYMBOL(g_adj));

  auto mmGrid = [](int N) { return dim3(4, (unsigned)((N + 63) / 64)); };

  auto build_csr = [&](const int* edges, int E, int N) {
    hipMemsetAsync(deg, 0, (size_t)N * sizeof(int), stream);
    k_count<<<(E + 255) / 256, 256, 0, stream>>>(edges, deg, E);
    k_scan<<<1, 1024, 0, stream>>>(deg, rowptr, cursor, N);
    k_fill<<<(E + 255) / 256, 256, 0, stream>>>(edges, cursor, adj, E);
  };

  auto gconv_hidden = [&](float*& X, float*& Y, const float* wh, const float* bh,
                          int E, int N) {
    for (int l = 0; l < 12; ++l) {
      const float* w0 = wh + (size_t)l * 2 * HID * HID;
      const float* w1 = w0 + (size_t)HID * HID;
      const float* b0 = bh + (size_t)l * 2 * HID;
      const float* b1 = b0 + HID;
      k_matmul2<HID, false><<<mmGrid(N), 256, 0, stream>>>(X, w0, w1, b0, b1, Y, Hb, N);
      k_gather256<<<((size_t)N * 64 + 255) / 256, 256, 0, stream>>>(rowptr, adj, Hb, Y, N);
      std::swap(X, Y);
    }
  };

  auto gconv_out = [&](const float* X, const float* wo, const float* bo,
                       float* Cdst, const int* edges, int E, int N) {
    k_rowdot3<<<((size_t)N * 64 + 255) / 256, 256, 0, stream>>>(X, wo, bo, Cdst, N);
    k_rowdot3<<<((size_t)N * 64 + 255) / 256, 256, 0, stream>>>(X, wo + HID * 3, bo + 3, C2, N);
    k_scatter3<<<(E + 255) / 256, 256, 0, stream>>>(edges, C2, Cdst, E);
  };

  float* Xc; float* Yc;

  // ---------- Stage 1 ----------
  build_csr(edges1, E1, N1);
  k_transpose<<<56 * 56, 128, 0, stream>>>(conv64, T, 56 * 56);
  k_vert_align<<<N1, 128, 0, stream>>>(T, verts0, VA, N1, 56, 56);
  k_matmul2<128, false><<<mmGrid(N1), 256, 0, stream>>>(
      VA, w_in1, w_in1 + 128 * HID, b_in1, b_in1 + HID, A, Hb, N1);
  k_gather256<<<((size_t)N1 * 64 + 255) / 256, 256, 0, stream>>>(rowptr, adj, Hb, A, N1);
  Xc = A; Yc = B;
  gconv_hidden(Xc, Yc, w_h1, b_h1, E1, N1);           // x ends in Xc
  gconv_out(Xc, w_out1, b_out1, C0, edges1, E1, N1);  // c1 in C0
  k_subdiv3<<<(N2 + 255) / 256, 256, 0, stream>>>(C0, edges1, Vv, N1, E1);        // v2
  k_subdiv_feat<<<((size_t)N2 * 64 + 255) / 256, 256, 0, stream>>>(Xc, edges1, Yc, N1, E1); // hs

  // ---------- Stage 2 ----------
  build_csr(edges2, E2, N2);
  k_transpose<<<28 * 28, 128, 0, stream>>>(conv128, T, 28 * 28);
  k_vert_align<<<N2, 128, 0, stream>>>(T, Vv, VA, N2, 28, 28);
  {
    float* hs = Yc; float* X0 = Xc;
    const float* w0 = w_in2;                    // w[0], rows 0..127 for VA
    const float* w1 = w_in2 + (size_t)384 * HID; // w[1]
    k_matmul2<128, false><<<mmGrid(N2), 256, 0, stream>>>(
        VA, w0, w1, b_in2, b_in2 + HID, X0, Hb, N2);
    k_matmul2<HID, true><<<mmGrid(N2), 256, 0, stream>>>(
        hs, w0 + 128 * HID, w1 + 128 * HID, nullptr, nullptr, X0, Hb, N2);
    k_gather256<<<((size_t)N2 * 64 + 255) / 256, 256, 0, stream>>>(rowptr, adj, Hb, X0, N2);
  }
  gconv_hidden(Xc, Yc, w_h2, b_h2, E2, N2);
  gconv_out(Xc, w_out2, b_out2, C0, edges2, E2, N2);  // c2 in C0
  k_subdiv3<<<(N3 + 255) / 256, 256, 0, stream>>>(C0, edges2, Vv, N2, E2);        // v3
  k_subdiv_feat<<<((size_t)N3 * 64 + 255) / 256, 256, 0, stream>>>(Xc, edges2, Yc, N2, E2); // hs

  // ---------- Stage 3 ----------
  build_csr(edges3, E3, N3);
  k_transpose<<<14 * 14, 128, 0, stream>>>(conv256, T, 14 * 14);
  k_vert_align<<<N3, 128, 0, stream>>>(T, Vv, VA, N3, 14, 14);
  {
    float* hs = Yc; float* X0 = Xc;
    const float* w0 = w_in3;
    const float* w1 = w_in3 + (size_t)384 * HID;
    k_matmul2<128, false><<<mmGrid(N3), 256, 0, stream>>>(
        VA, w0, w1, b_in3, b_in3 + HID, X0, Hb, N3);
    k_matmul2<HID, true><<<mmGrid(N3), 256, 0, stream>>>(
        hs, w0 + 128 * HID, w1 + 128 * HID, nullptr, nullptr, X0, Hb, N3);
    k_gather256<<<((size_t)N3 * 64 + 255) / 256, 256, 0, stream>>>(rowptr, adj, Hb, X0, N3);
  }
  gconv_hidden(Xc, Yc, w_h3, b_h3, E3, N3);
  // final coords straight into d_out
  float* OUT = (float*)d_out;
  k_rowdot3<<<((size_t)N3 * 64 + 255) / 256, 256, 0, stream>>>(Xc, w_out3, b_out3, OUT, N3);
  k_rowdot3<<<((size_t)N3 * 64 + 255) / 256, 256, 0, stream>>>(Xc, w_out3 + HID * 3, b_out3 + 3, C2, N3);
  k_scatter3<<<(E3 + 255) / 256, 256, 0, stream>>>(edges3, C2, OUT, E3);
}

// Round 4
// 5879.329 us; speedup vs baseline: 7.5982x; 1.6506x over previous
//
#include <hip/hip_runtime.h>
#include <utility>

#define HID 256

typedef __attribute__((ext_vector_type(8))) short bf16x8;
typedef __attribute__((ext_vector_type(4))) float f32x4;
typedef __attribute__((ext_vector_type(4))) unsigned short us4;

// Topology constants for GRID_N=80
constexpr size_t MAXN3 = 100489;
constexpr size_t MAXE3 = 300200;

// Transposed-weight scratch offsets (elements). Layout per matrix: [256 n][K k].
constexpr size_t OFF_IN1 = 0;                       // 2 mats K=128
constexpr size_t OFF_IN2 = OFF_IN1 + 2 * 256 * 128; // 2 mats K=384
constexpr size_t OFF_IN3 = OFF_IN2 + 2 * 256 * 384;
constexpr size_t OFF_H1  = OFF_IN3 + 2 * 256 * 384; // 24 mats K=256
constexpr size_t OFF_H2  = OFF_H1 + 24 * 256 * 256;
constexpr size_t OFF_H3  = OFF_H2 + 24 * 256 * 256;
constexpr size_t WT_TOTAL = OFF_H3 + 24 * 256 * 256; // 5,177,344

// Static device scratch (BSS — graph-capture safe).
__device__ float g_A [MAXN3 * 256];
__device__ float g_B [MAXN3 * 256];
__device__ float g_Hb[MAXN3 * 256];
__device__ float g_VA[MAXN3 * 128];
__device__ float g_C0[MAXN3 * 3];
__device__ float g_C2[MAXN3 * 3];
__device__ float g_Vv[MAXN3 * 3];
__device__ float g_T [56 * 56 * 128];
__device__ unsigned short g_Wth[WT_TOTAL];
__device__ unsigned short g_Wtl[WT_TOTAL];
// CSR scratch
__device__ int g_deg   [MAXN3];
__device__ int g_rowptr[MAXN3 + 1];
__device__ int g_cursor[MAXN3];
__device__ int g_adj   [2 * MAXE3];

// ---------------- weight transpose + bf16 hi/lo split ----------------
// In: mats of [K][256] f32 (contiguous). Out: mats of [256][K] hi/lo bf16.
__global__ __launch_bounds__(256) void k_wtrans(const float* __restrict__ W,
                                                unsigned short* __restrict__ Oh,
                                                unsigned short* __restrict__ Ol,
                                                int K) {
  __shared__ float t[32][33];
  int mat = blockIdx.z;
  const float* Wm = W + (size_t)mat * K * 256;
  unsigned short* OhM = Oh + (size_t)mat * K * 256;
  unsigned short* OlM = Ol + (size_t)mat * K * 256;
  int x = threadIdx.x;            // 0..31
  int y = threadIdx.y;            // 0..7
  int k0 = blockIdx.x * 32, n0 = blockIdx.y * 32;
#pragma unroll
  for (int i = 0; i < 4; ++i) {
    int kk = y + i * 8;
    t[kk][x] = Wm[(size_t)(k0 + kk) * 256 + n0 + x];
  }
  __syncthreads();
#pragma unroll
  for (int i = 0; i < 4; ++i) {
    int nn = y + i * 8;
    float v = t[x][nn];
    unsigned u = __float_as_uint(v);
    unsigned short hi = (unsigned short)(u >> 16);
    float hv = __uint_as_float((unsigned)hi << 16);
    unsigned short lo = (unsigned short)(__float_as_uint(v - hv) >> 16);
    OhM[(size_t)(n0 + nn) * K + k0 + x] = hi;
    OlM[(size_t)(n0 + nn) * K + k0 + x] = lo;
  }
}

// ---------------- CSR build ----------------

__global__ __launch_bounds__(256) void k_count(const int* __restrict__ edges,
                                               int* __restrict__ deg, int E) {
  int e = blockIdx.x * blockDim.x + threadIdx.x;
  if (e >= E) return;
  atomicAdd(&deg[edges[2 * e + 0]], 1);
  atomicAdd(&deg[edges[2 * e + 1]], 1);
}

__global__ __launch_bounds__(1024) void k_scan(const int* __restrict__ deg,
                                               int* __restrict__ rowptr,
                                               int* __restrict__ cursor, int N) {
  __shared__ int sums[1024];
  int t = threadIdx.x;
  int chunk = (N + 1023) / 1024;
  int lo = t * chunk;
  int hi = min(lo + chunk, N);
  int s = 0;
  for (int i = lo; i < hi; ++i) s += deg[i];
  sums[t] = s;
  __syncthreads();
  for (int off = 1; off < 1024; off <<= 1) {
    int v = (t >= off) ? sums[t - off] : 0;
    __syncthreads();
    sums[t] += v;
    __syncthreads();
  }
  int base = (t == 0) ? 0 : sums[t - 1];
  for (int i = lo; i < hi; ++i) {
    rowptr[i] = base;
    cursor[i] = base;
    base += deg[i];
  }
  if (t == 1023) rowptr[N] = sums[1023];
}

__global__ __launch_bounds__(256) void k_fill(const int* __restrict__ edges,
                                              int* __restrict__ cursor,
                                              int* __restrict__ adj, int E) {
  int e = blockIdx.x * blockDim.x + threadIdx.x;
  if (e >= E) return;
  int a = edges[2 * e + 0];
  int b = edges[2 * e + 1];
  adj[atomicAdd(&cursor[a], 1)] = b;
  adj[atomicAdd(&cursor[b], 1)] = a;
}

// ---------------- misc kernels ----------------

__global__ __launch_bounds__(128) void k_transpose(const float* __restrict__ in,
                                                   float* __restrict__ out, int HW) {
  int p = blockIdx.x;
  int c = threadIdx.x;
  if (p < HW) out[(size_t)p * 128 + c] = in[(size_t)c * HW + p];
}

__global__ __launch_bounds__(128) void k_vert_align(const float* __restrict__ fT,
                                                    const float* __restrict__ verts,
                                                    float* __restrict__ out,
                                                    int N, int H, int W) {
  int v = blockIdx.x;
  if (v >= N) return;
  int c = threadIdx.x;
  float vx = verts[(size_t)v * 3 + 0];
  float vy = verts[(size_t)v * 3 + 1];
  float fx = (vx + 1.f) * 0.5f * (float)(W - 1);
  float fy = (vy + 1.f) * 0.5f * (float)(H - 1);
  float x0f = floorf(fx), y0f = floorf(fy);
  float wx = fx - x0f, wy = fy - y0f;
  int x0 = (int)x0f, y0 = (int)y0f;
  float acc = 0.f;
#pragma unroll
  for (int dy = 0; dy < 2; ++dy) {
#pragma unroll
    for (int dx = 0; dx < 2; ++dx) {
      int yi = y0 + dy, xi = x0 + dx;
      bool valid = (yi >= 0) && (yi < H) && (xi >= 0) && (xi < W);
      int yc = min(max(yi, 0), H - 1);
      int xc = min(max(xi, 0), W - 1);
      float val = fT[((size_t)yc * W + xc) * 128 + c];
      float wgt = (dy ? wy : 1.f - wy) * (dx ? wx : 1.f - wx);
      acc += valid ? val * wgt : 0.f;
    }
  }
  out[(size_t)v * 128 + c] = acc;
}

// ---------------- MFMA split-bf16 dual matmul ----------------
// Y0 = X@W0 (+b0 | +=), Y1 = X@W1 (+b1 | +=).  W* are pre-transposed [256 n][ldW k]
// bf16 hi/lo, pointers pre-offset to the k-slice. X is f32 [N][ldX].
// LDS swizzle: 8-elem (16B) slot index XORed with (row&7) — conflict-free b128 reads.
#define SWZ(row, slot) (((row) * 64) + (((slot) ^ ((row) & 7)) * 8))

template <bool ACC>
__global__ __launch_bounds__(256) void k_mfma2(const float* __restrict__ X, int ldX, int Kmm,
                                               const unsigned short* __restrict__ w0h,
                                               const unsigned short* __restrict__ w0l,
                                               const unsigned short* __restrict__ w1h,
                                               const unsigned short* __restrict__ w1l,
                                               int ldW,
                                               const float* __restrict__ b0,
                                               const float* __restrict__ b1,
                                               float* __restrict__ Y0,
                                               float* __restrict__ Y1, int N) {
  __shared__ unsigned short lds[6][64 * 64]; // xhi,xlo,w0h,w0l,w1h,w1l
  int tid = threadIdx.x;
  int lane = tid & 63;
  int wid = tid >> 6;
  int wm = wid & 1, wn = wid >> 1;
  int row0 = blockIdx.y * 64;
  int col0 = blockIdx.x * 64;

  f32x4 acc[2][2][2];
#pragma unroll
  for (int w = 0; w < 2; ++w)
#pragma unroll
    for (int m = 0; m < 2; ++m)
#pragma unroll
      for (int n = 0; n < 2; ++n) acc[w][m][n] = (f32x4){0.f, 0.f, 0.f, 0.f};

  const unsigned short* wsrc[4] = {w0h, w0l, w1h, w1l};

  for (int kt = 0; kt < Kmm; kt += 64) {
    // stage X tile (f32 -> bf16 hi/lo, swizzled)
#pragma unroll
    for (int it = 0; it < 4; ++it) {
      int linear = tid + it * 256;
      int row = linear >> 4;
      int col4 = (linear & 15) * 4;
      float4 xv = make_float4(0.f, 0.f, 0.f, 0.f);
      if (row0 + row < N)
        xv = *(const float4*)(X + (size_t)(row0 + row) * ldX + kt + col4);
      us4 hv, lv;
#pragma unroll
      for (int j = 0; j < 4; ++j) {
        float v = (&xv.x)[j];
        unsigned u = __float_as_uint(v);
        unsigned short hi = (unsigned short)(u >> 16);
        float hf = __uint_as_float((unsigned)hi << 16);
        unsigned short lo = (unsigned short)(__float_as_uint(v - hf) >> 16);
        hv[j] = hi;
        lv[j] = lo;
      }
      int s = col4 >> 3, h = (col4 >> 2) & 1;
      int off = SWZ(row, s) + h * 4;
      *(us4*)&lds[0][off] = hv;
      *(us4*)&lds[1][off] = lv;
    }
    // stage W tiles (already bf16, swizzled)
#pragma unroll
    for (int a = 0; a < 4; ++a) {
      const unsigned short* src = wsrc[a];
#pragma unroll
      for (int it = 0; it < 2; ++it) {
        int linear = tid + it * 256;
        int n = linear >> 3;
        int slot = linear & 7;
        uint4 v = *(const uint4*)(src + (size_t)(col0 + n) * ldW + kt + slot * 8);
        *(uint4*)&lds[2 + a][SWZ(n, slot)] = v;
      }
    }
    __syncthreads();
#pragma unroll
    for (int ks = 0; ks < 2; ++ks) {
      int slot = ks * 4 + (lane >> 4);
      bf16x8 ah[2], al[2];
#pragma unroll
      for (int m = 0; m < 2; ++m) {
        int row = wm * 32 + m * 16 + (lane & 15);
        ah[m] = *(const bf16x8*)&lds[0][SWZ(row, slot)];
        al[m] = *(const bf16x8*)&lds[1][SWZ(row, slot)];
      }
      bf16x8 bh[2][2], bl[2][2];
#pragma unroll
      for (int w = 0; w < 2; ++w)
#pragma unroll
        for (int n = 0; n < 2; ++n) {
          int nr = wn * 32 + n * 16 + (lane & 15);
          bh[w][n] = *(const bf16x8*)&lds[2 + 2 * w][SWZ(nr, slot)];
          bl[w][n] = *(const bf16x8*)&lds[3 + 2 * w][SWZ(nr, slot)];
        }
#pragma unroll
      for (int w = 0; w < 2; ++w)
#pragma unroll
        for (int m = 0; m < 2; ++m)
#pragma unroll
          for (int n = 0; n < 2; ++n) {
            f32x4 c = acc[w][m][n];
            c = __builtin_amdgcn_mfma_f32_16x16x32_bf16(al[m], bh[w][n], c, 0, 0, 0);
            c = __builtin_amdgcn_mfma_f32_16x16x32_bf16(ah[m], bl[w][n], c, 0, 0, 0);
            c = __builtin_amdgcn_mfma_f32_16x16x32_bf16(ah[m], bh[w][n], c, 0, 0, 0);
            acc[w][m][n] = c;
          }
    }
    __syncthreads();
  }

  // epilogue: D row = (lane>>4)*4 + r (within 16), col = lane&15 (m89-verified)
#pragma unroll
  for (int w = 0; w < 2; ++w) {
    float* Yp = w ? Y1 : Y0;
    const float* bp = w ? b1 : b0;
#pragma unroll
    for (int m = 0; m < 2; ++m)
#pragma unroll
      for (int n = 0; n < 2; ++n) {
        int col = col0 + wn * 32 + n * 16 + (lane & 15);
        int rbase = row0 + wm * 32 + m * 16 + (lane >> 4) * 4;
        f32x4 v = acc[w][m][n];
#pragma unroll
        for (int r = 0; r < 4; ++r) {
          int row = rbase + r;
          if (row < N) {
            if (ACC)
              Yp[(size_t)row * HID + col] += v[r];
            else
              Yp[(size_t)row * HID + col] = v[r] + bp[col];
          }
        }
      }
  }
}

// Y[v] += sum_{u in adj(v)} H[u]
__global__ __launch_bounds__(256) void k_gather256(const int* __restrict__ rowptr,
                                                   const int* __restrict__ adj,
                                                   const float* __restrict__ H,
                                                   float* __restrict__ Y, int N) {
  int idx = blockIdx.x * blockDim.x + threadIdx.x;
  int v = idx >> 6;
  if (v >= N) return;
  int c = (threadIdx.x & 63) * 4;
  int lo = rowptr[v], hi = rowptr[v + 1];
  float* yp = Y + (size_t)v * HID + c;
  float4 acc = *(float4*)yp;
  for (int i = lo; i < hi; ++i) {
    float4 h = *(const float4*)(H + (size_t)adj[i] * HID + c);
    acc.x += h.x; acc.y += h.y; acc.z += h.z; acc.w += h.w;
  }
  *(float4*)yp = acc;
}

__global__ __launch_bounds__(256) void k_rowdot3(const float* __restrict__ X,
                                                 const float* __restrict__ W,
                                                 const float* __restrict__ b,
                                                 float* __restrict__ Y, int N) {
  int gid = blockIdx.x * blockDim.x + threadIdx.x;
  int row = gid >> 6;
  int lane = threadIdx.x & 63;
  if (row >= N) return;
  float4 xv = ((const float4*)(X + (size_t)row * HID))[lane];
  float s0 = 0.f, s1 = 0.f, s2 = 0.f;
#pragma unroll
  for (int k = 0; k < 4; ++k) {
    float x = (&xv.x)[k];
    int kk = lane * 4 + k;
    s0 += x * W[kk * 3 + 0];
    s1 += x * W[kk * 3 + 1];
    s2 += x * W[kk * 3 + 2];
  }
#pragma unroll
  for (int off = 32; off > 0; off >>= 1) {
    s0 += __shfl_down(s0, off);
    s1 += __shfl_down(s1, off);
    s2 += __shfl_down(s2, off);
  }
  if (lane == 0) {
    Y[(size_t)row * 3 + 0] = s0 + b[0];
    Y[(size_t)row * 3 + 1] = s1 + b[1];
    Y[(size_t)row * 3 + 2] = s2 + b[2];
  }
}

__global__ __launch_bounds__(256) void k_scatter3(const int* __restrict__ edges,
                                                  const float* __restrict__ H,
                                                  float* __restrict__ OUT, int E) {
  int e = blockIdx.x * blockDim.x + threadIdx.x;
  if (e >= E) return;
  int a = edges[(size_t)e * 2 + 0];
  int b = edges[(size_t)e * 2 + 1];
#pragma unroll
  for (int k = 0; k < 3; ++k) {
    atomicAdd(&OUT[(size_t)a * 3 + k], H[(size_t)b * 3 + k]);
    atomicAdd(&OUT[(size_t)b * 3 + k], H[(size_t)a * 3 + k]);
  }
}

__global__ __launch_bounds__(256) void k_subdiv3(const float* __restrict__ c,
                                                 const int* __restrict__ edges,
                                                 float* __restrict__ v, int N, int E) {
  int i = blockIdx.x * blockDim.x + threadIdx.x;
  if (i >= N + E) return;
  if (i < N) {
#pragma unroll
    for (int k = 0; k < 3; ++k) v[(size_t)i * 3 + k] = c[(size_t)i * 3 + k];
  } else {
    int e = i - N;
    int a = edges[(size_t)e * 2 + 0];
    int b = edges[(size_t)e * 2 + 1];
#pragma unroll
    for (int k = 0; k < 3; ++k)
      v[(size_t)i * 3 + k] = 0.5f * (c[(size_t)a * 3 + k] + c[(size_t)b * 3 + k]);
  }
}

__global__ __launch_bounds__(256) void k_subdiv_feat(const float* __restrict__ x,
                                                     const int* __restrict__ edges,
                                                     float* __restrict__ out, int N, int E) {
  int idx = blockIdx.x * blockDim.x + threadIdx.x;
  int v = idx >> 6;
  if (v >= N + E) return;
  int c = (threadIdx.x & 63) * 4;
  float4 r;
  if (v < N) {
    r = *(const float4*)(x + (size_t)v * HID + c);
  } else {
    int e = v - N;
    int a = edges[(size_t)e * 2 + 0];
    int b = edges[(size_t)e * 2 + 1];
    float4 xa = *(const float4*)(x + (size_t)a * HID + c);
    float4 xb = *(const float4*)(x + (size_t)b * HID + c);
    r = make_float4(0.5f * (xa.x + xb.x), 0.5f * (xa.y + xb.y),
                    0.5f * (xa.z + xb.z), 0.5f * (xa.w + xb.w));
  }
  *(float4*)(out + (size_t)v * HID + c) = r;
}

// ---------------- launcher ----------------

extern "C" void kernel_launch(void* const* d_in, const int* in_sizes, int n_in,
                              void* d_out, int out_size, void* d_ws, size_t ws_size,
                              hipStream_t stream) {
  const float* conv64  = (const float*)d_in[0];
  const float* conv128 = (const float*)d_in[1];
  const float* conv256 = (const float*)d_in[2];
  const float* verts0  = (const float*)d_in[3];
  const int*   edges1  = (const int*)d_in[4];
  const int*   edges2  = (const int*)d_in[5];
  const int*   edges3  = (const int*)d_in[6];
  const float* w_in1 = (const float*)d_in[7],  *b_in1 = (const float*)d_in[8];
  const float* w_h1  = (const float*)d_in[9],  *b_h1  = (const float*)d_in[10];
  const float* w_out1= (const float*)d_in[11], *b_out1= (const float*)d_in[12];
  const float* w_in2 = (const float*)d_in[13], *b_in2 = (const float*)d_in[14];
  const float* w_h2  = (const float*)d_in[15], *b_h2  = (const float*)d_in[16];
  const float* w_out2= (const float*)d_in[17], *b_out2= (const float*)d_in[18];
  const float* w_in3 = (const float*)d_in[19], *b_in3 = (const float*)d_in[20];
  const float* w_h3  = (const float*)d_in[21], *b_h3  = (const float*)d_in[22];
  const float* w_out3= (const float*)d_in[23], *b_out3= (const float*)d_in[24];

  const int N1 = in_sizes[3] / 3;
  const int E1 = in_sizes[4] / 2;
  const int E2 = in_sizes[5] / 2;
  const int E3 = in_sizes[6] / 2;
  const int N2 = N1 + E1;
  const int N3 = N2 + E2;
  if ((size_t)N3 > MAXN3 || (size_t)E3 > MAXE3) return;

  float *A, *B, *Hb, *VA, *C0, *C2, *Vv, *T;
  unsigned short *Wth, *Wtl;
  int *deg, *rowptr, *cursor, *adj;
  hipGetSymbolAddress((void**)&A,  HIP_SYMBOL(g_A));
  hipGetSymbolAddress((void**)&B,  HIP_SYMBOL(g_B));
  hipGetSymbolAddress((void**)&Hb, HIP_SYMBOL(g_Hb));
  hipGetSymbolAddress((void**)&VA, HIP_SYMBOL(g_VA));
  hipGetSymbolAddress((void**)&C0, HIP_SYMBOL(g_C0));
  hipGetSymbolAddress((void**)&C2, HIP_SYMBOL(g_C2));
  hipGetSymbolAddress((void**)&Vv, HIP_SYMBOL(g_Vv));
  hipGetSymbolAddress((void**)&T,  HIP_SYMBOL(g_T));
  hipGetSymbolAddress((void**)&Wth, HIP_SYMBOL(g_Wth));
  hipGetSymbolAddress((void**)&Wtl, HIP_SYMBOL(g_Wtl));
  hipGetSymbolAddress((void**)&deg,    HIP_SYMBOL(g_deg));
  hipGetSymbolAddress((void**)&rowptr, HIP_SYMBOL(g_rowptr));
  hipGetSymbolAddress((void**)&cursor, HIP_SYMBOL(g_cursor));
  hipGetSymbolAddress((void**)&adj,    HIP_SYMBOL(g_adj));

  // ---- weight transpose + split (once per launch, deterministic) ----
  k_wtrans<<<dim3(4, 8, 2),  dim3(32, 8), 0, stream>>>(w_in1, Wth + OFF_IN1, Wtl + OFF_IN1, 128);
  k_wtrans<<<dim3(12, 8, 2), dim3(32, 8), 0, stream>>>(w_in2, Wth + OFF_IN2, Wtl + OFF_IN2, 384);
  k_wtrans<<<dim3(12, 8, 2), dim3(32, 8), 0, stream>>>(w_in3, Wth + OFF_IN3, Wtl + OFF_IN3, 384);
  k_wtrans<<<dim3(8, 8, 24), dim3(32, 8), 0, stream>>>(w_h1,  Wth + OFF_H1,  Wtl + OFF_H1,  256);
  k_wtrans<<<dim3(8, 8, 24), dim3(32, 8), 0, stream>>>(w_h2,  Wth + OFF_H2,  Wtl + OFF_H2,  256);
  k_wtrans<<<dim3(8, 8, 24), dim3(32, 8), 0, stream>>>(w_h3,  Wth + OFF_H3,  Wtl + OFF_H3,  256);

  auto mmGrid = [](int N) { return dim3(4, (unsigned)((N + 63) / 64)); };

  auto build_csr = [&](const int* edges, int E, int N) {
    hipMemsetAsync(deg, 0, (size_t)N * sizeof(int), stream);
    k_count<<<(E + 255) / 256, 256, 0, stream>>>(edges, deg, E);
    k_scan<<<1, 1024, 0, stream>>>(deg, rowptr, cursor, N);
    k_fill<<<(E + 255) / 256, 256, 0, stream>>>(edges, cursor, adj, E);
  };

  auto gconv_hidden = [&](float*& X, float*& Y, size_t offH, const float* bh, int N) {
    for (int l = 0; l < 12; ++l) {
      const unsigned short* w0h = Wth + offH + (size_t)(2 * l + 0) * 65536;
      const unsigned short* w0l = Wtl + offH + (size_t)(2 * l + 0) * 65536;
      const unsigned short* w1h = Wth + offH + (size_t)(2 * l + 1) * 65536;
      const unsigned short* w1l = Wtl + offH + (size_t)(2 * l + 1) * 65536;
      const float* b0 = bh + (size_t)l * 2 * HID;
      const float* b1 = b0 + HID;
      k_mfma2<false><<<mmGrid(N), 256, 0, stream>>>(X, 256, 256, w0h, w0l, w1h, w1l, 256,
                                                    b0, b1, Y, Hb, N);
      k_gather256<<<((size_t)N * 64 + 255) / 256, 256, 0, stream>>>(rowptr, adj, Hb, Y, N);
      std::swap(X, Y);
    }
  };

  auto gconv_out = [&](const float* X, const float* wo, const float* bo,
                       float* Cdst, const int* edges, int E, int N) {
    k_rowdot3<<<((size_t)N * 64 + 255) / 256, 256, 0, stream>>>(X, wo, bo, Cdst, N);
    k_rowdot3<<<((size_t)N * 64 + 255) / 256, 256, 0, stream>>>(X, wo + HID * 3, bo + 3, C2, N);
    k_scatter3<<<(E + 255) / 256, 256, 0, stream>>>(edges, C2, Cdst, E);
  };

  float* Xc; float* Yc;

  // ---------- Stage 1 ----------
  build_csr(edges1, E1, N1);
  k_transpose<<<56 * 56, 128, 0, stream>>>(conv64, T, 56 * 56);
  k_vert_align<<<N1, 128, 0, stream>>>(T, verts0, VA, N1, 56, 56);
  k_mfma2<false><<<mmGrid(N1), 256, 0, stream>>>(
      VA, 128, 128,
      Wth + OFF_IN1, Wtl + OFF_IN1, Wth + OFF_IN1 + 32768, Wtl + OFF_IN1 + 32768, 128,
      b_in1, b_in1 + HID, A, Hb, N1);
  k_gather256<<<((size_t)N1 * 64 + 255) / 256, 256, 0, stream>>>(rowptr, adj, Hb, A, N1);
  Xc = A; Yc = B;
  gconv_hidden(Xc, Yc, OFF_H1, b_h1, N1);
  gconv_out(Xc, w_out1, b_out1, C0, edges1, E1, N1);  // c1
  k_subdiv3<<<(N2 + 255) / 256, 256, 0, stream>>>(C0, edges1, Vv, N1, E1);        // v2
  k_subdiv_feat<<<((size_t)N2 * 64 + 255) / 256, 256, 0, stream>>>(Xc, edges1, Yc, N1, E1); // hs

  // ---------- Stage 2 ----------
  build_csr(edges2, E2, N2);
  k_transpose<<<28 * 28, 128, 0, stream>>>(conv128, T, 28 * 28);
  k_vert_align<<<N2, 128, 0, stream>>>(T, Vv, VA, N2, 28, 28);
  {
    float* hs = Yc; float* X0 = Xc;
    const size_t m0 = OFF_IN2, m1 = OFF_IN2 + (size_t)256 * 384;
    k_mfma2<false><<<mmGrid(N2), 256, 0, stream>>>(
        VA, 128, 128, Wth + m0, Wtl + m0, Wth + m1, Wtl + m1, 384,
        b_in2, b_in2 + HID, X0, Hb, N2);
    k_mfma2<true><<<mmGrid(N2), 256, 0, stream>>>(
        hs, 256, 256, Wth + m0 + 128, Wtl + m0 + 128, Wth + m1 + 128, Wtl + m1 + 128, 384,
        nullptr, nullptr, X0, Hb, N2);
    k_gather256<<<((size_t)N2 * 64 + 255) / 256, 256, 0, stream>>>(rowptr, adj, Hb, X0, N2);
  }
  gconv_hidden(Xc, Yc, OFF_H2, b_h2, N2);
  gconv_out(Xc, w_out2, b_out2, C0, edges2, E2, N2);  // c2
  k_subdiv3<<<(N3 + 255) / 256, 256, 0, stream>>>(C0, edges2, Vv, N2, E2);        // v3
  k_subdiv_feat<<<((size_t)N3 * 64 + 255) / 256, 256, 0, stream>>>(Xc, edges2, Yc, N2, E2); // hs

  // ---------- Stage 3 ----------
  build_csr(edges3, E3, N3);
  k_transpose<<<14 * 14, 128, 0, stream>>>(conv256, T, 14 * 14);
  k_vert_align<<<N3, 128, 0, stream>>>(T, Vv, VA, N3, 14, 14);
  {
    float* hs = Yc; float* X0 = Xc;
    const size_t m0 = OFF_IN3, m1 = OFF_IN3 + (size_t)256 * 384;
    k_mfma2<false><<<mmGrid(N3), 256, 0, stream>>>(
        VA, 128, 128, Wth + m0, Wtl + m0, Wth + m1, Wtl + m1, 384,
        b_in3, b_in3 + HID, X0, Hb, N3);
    k_mfma2<true><<<mmGrid(N3), 256, 0, stream>>>(
        hs, 256, 256, Wth + m0 + 128, Wtl + m0 + 128, Wth + m1 + 128, Wtl + m1 + 128, 384,
        nullptr, nullptr, X0, Hb, N3);
    k_gather256<<<((size_t)N3 * 64 + 255) / 256, 256, 0, stream>>>(rowptr, adj, Hb, X0, N3);
  }
  gconv_hidden(Xc, Yc, OFF_H3, b_h3, N3);
  float* OUT = (float*)d_out;
  k_rowdot3<<<((size_t)N3 * 64 + 255) / 256, 256, 0, stream>>>(Xc, w_out3, b_out3, OUT, N3);
  k_rowdot3<<<((size_t)N3 * 64 + 255) / 256, 256, 0, stream>>>(Xc, w_out3 + HID * 3, b_out3 + 3, C2, N3);
  k_scatter3<<<(E3 + 255) / 256, 256, 0, stream>>>(edges3, C2, OUT, E3);
}